// Round 3
// baseline (251.336 us; speedup 1.0000x reference)
//
#include <hip/hip_runtime.h>
#include <math.h>

#define Nn 64
#define Tt 200
#define Bb 64

__device__ __forceinline__ float sigm(float x){ return 1.0f/(1.0f+__expf(-x)); }
__device__ __forceinline__ float tanh_fast(float x){
  x = fminf(fmaxf(x, -15.f), 15.f);
  float e = __expf(-2.f*x);
  return (1.f - e)/(1.f + e);
}

typedef __attribute__((ext_vector_type(8))) short bf16x8;
typedef __attribute__((ext_vector_type(4))) float f32x4;

__device__ __forceinline__ ushort f2bf(float f){          // RNE f32->bf16
  unsigned u = __float_as_uint(f);
  unsigned r = (u + 0x7fffu + ((u>>16)&1u)) >> 16;
  return (ushort)r;
}
__device__ __forceinline__ float bf2f(ushort h){ return __uint_as_float(((unsigned)h)<<16); }

// ---------------------------------------------------------------------------
// K1: build graph operators. L = -S_cheb, L2 = 2*S@S - I, G = S_gcn (+diag).
// Single block, 256 threads. Edge scatter via LDS atomics; S padded to
// stride 68 so the S@S phase uses conflict-free f4 row reads.
// ---------------------------------------------------------------------------
__global__ __launch_bounds__(256) void k1_graphs(
    const int* __restrict__ sp_ei, const float* __restrict__ sp_ew,
    const int* __restrict__ fn_ei, const float* __restrict__ fn_ew,
    float* __restrict__ Lg, float* __restrict__ L2g, float* __restrict__ Gm)
{
  __shared__ float deg[Nn];
  __shared__ float dinv[Nn];
  __shared__ float S[64*68];            // padded stride 68
  const int tid = threadIdx.x;

  // ---- ChebConv operator (512 edges) ----
  if (tid < Nn) deg[tid] = 0.f;
  for (int i=tid;i<64*68;i+=256) S[i]=0.f;
  __syncthreads();
  for (int e=tid;e<512;e+=256) atomicAdd(&deg[sp_ei[e]], sp_ew[e]);   // deg over row
  __syncthreads();
  if (tid < Nn) dinv[tid] = (deg[tid] > 0.f) ? rsqrtf(deg[tid]) : 0.f;
  __syncthreads();
  for (int e=tid;e<512;e+=256) {
    int r = sp_ei[e], c = sp_ei[512+e];
    atomicAdd(&S[c*68 + r], dinv[r]*sp_ew[e]*dinv[c]);
  }
  __syncthreads();
  for (int i=tid;i<4096;i+=256) Lg[i] = -S[(i>>6)*68 + (i&63)];   // Ltil = -S
  // L2 = 2*S@S - I : thread -> row n = tid>>2, 16 cols at mb=(tid&3)*16
  {
    const int n = tid>>2, mb = (tid&3)*16;
    float a[16];
    #pragma unroll
    for (int q=0;q<16;q++) a[q]=0.f;
    for (int j=0;j<64;j++){
      float snj = S[n*68+j];
      const float4* rj = (const float4*)&S[j*68+mb];
      #pragma unroll
      for (int q=0;q<4;q++){
        float4 v = rj[q];
        a[q*4+0]=fmaf(snj,v.x,a[q*4+0]);
        a[q*4+1]=fmaf(snj,v.y,a[q*4+1]);
        a[q*4+2]=fmaf(snj,v.z,a[q*4+2]);
        a[q*4+3]=fmaf(snj,v.w,a[q*4+3]);
      }
    }
    #pragma unroll
    for (int q=0;q<16;q++){
      int m = mb+q;
      L2g[n*64+m] = 2.f*a[q] - (n==m ? 1.f : 0.f);
    }
  }
  __syncthreads();   // all reads of S done before reuse

  // ---- GCNConv operator (1024 edges) ----
  if (tid < Nn) deg[tid] = 0.f;
  for (int i=tid;i<64*68;i+=256) S[i]=0.f;
  __syncthreads();
  for (int e=tid;e<1024;e+=256) atomicAdd(&deg[fn_ei[1024+e]], fn_ew[e]);  // deg over col
  __syncthreads();
  if (tid < Nn) dinv[tid] = rsqrtf(deg[tid] + 1.f);
  __syncthreads();
  for (int e=tid;e<1024;e+=256) {
    int r = fn_ei[e], c = fn_ei[1024+e];
    atomicAdd(&S[c*68 + r], dinv[r]*fn_ew[e]*dinv[c]);
  }
  __syncthreads();
  if (tid < Nn) S[tid*68 + tid] += dinv[tid]*dinv[tid];     // + diag(1/deg)
  __syncthreads();
  for (int i=tid;i<4096;i+=256) Gm[i] = S[(i>>6)*68 + (i&63)];
}

// ---------------------------------------------------------------------------
// K2: fold Wih (+Wcheb/Wgcn/graph ops) into Aeff[384][64] and constv[384].
// ---------------------------------------------------------------------------
__global__ __launch_bounds__(64) void k2_aeff(
    const float* __restrict__ Wih_f, const float* __restrict__ bih_f,
    const float* __restrict__ Wih_b, const float* __restrict__ bih_b,
    const float* __restrict__ Wcheb, const float* __restrict__ bcheb,
    const float* __restrict__ Wgcn,  const float* __restrict__ bgcn,
    const float* __restrict__ Lg, const float* __restrict__ L2g,
    const float* __restrict__ Gm,
    float* __restrict__ Aeff, float* __restrict__ constv)
{
  const int g = blockIdx.x;                 // 0..383
  const int dir = (g >= 192) ? 1 : 0;
  const int grow = dir ? g - 192 : g;
  const float* Wih = dir ? Wih_b : Wih_f;
  const float* bih = dir ? bih_b : bih_f;

  __shared__ float wrow[64*129];
  __shared__ float arow[256];
  const int tid = threadIdx.x;              // 64 threads = 1 wave

  for (int i = tid; i < 8192; i += 64)
    wrow[(i>>7)*129 + (i&127)] = Wih[grow*8192 + i];
  __syncthreads();

  const int n = tid;
  float a0=0.f,a1=0.f,a2=0.f,a3=0.f,cp=0.f;
  for (int c=0;c<64;c++) {
    float w1 = wrow[n*129 + c];
    a0 = fmaf(w1, Wcheb[c],     a0);
    a1 = fmaf(w1, Wcheb[64+c],  a1);
    a2 = fmaf(w1, Wcheb[128+c], a2);
    cp = fmaf(w1, bcheb[c],     cp);
    float w2 = wrow[n*129 + 64 + c];
    a3 = fmaf(w2, Wgcn[c], a3);
    cp = fmaf(w2, bgcn[c], cp);
  }
  arow[n*4+0]=a0; arow[n*4+1]=a1; arow[n*4+2]=a2; arow[n*4+3]=a3;
  for (int off=32; off; off>>=1) cp += __shfl_down(cp, off, 64);
  if (tid==0) constv[g] = cp + bih[grow];
  __syncthreads();

  const int m = tid;
  float ae = arow[m*4+0];
  for (int nn2=0; nn2<64; nn2++) {
    ae = fmaf(arow[nn2*4+1], Lg [nn2*64+m], ae);
    ae = fmaf(arow[nn2*4+2], L2g[nn2*64+m], ae);
    ae = fmaf(arow[nn2*4+3], Gm [nn2*64+m], ae);
  }
  Aeff[g*64+m] = ae;
}

// ---------------------------------------------------------------------------
// K3: transpose x[B][N][T] -> xTr[B*T][N]
// ---------------------------------------------------------------------------
__global__ __launch_bounds__(256) void k3_transpose(
    const float* __restrict__ x, float* __restrict__ xTr)
{
  const int b = blockIdx.x;
  for (int idx = threadIdx.x; idx < Tt*Nn; idx += 256) {
    int t = idx >> 6, m = idx & 63;
    xTr[(b*Tt + t)*64 + m] = x[(b*64 + m)*Tt + t];
  }
}

// ---------------------------------------------------------------------------
// K4: xp[12800][384] = xTr[12800][64] @ Aeff[384][64]^T + constv
// ---------------------------------------------------------------------------
__global__ __launch_bounds__(256) void k4_gemm(
    const float* __restrict__ xTr, const float* __restrict__ Aeff,
    const float* __restrict__ constv, float* __restrict__ xp)
{
  const int m0 = blockIdx.x*64, g0 = blockIdx.y*64;
  __shared__ float sX[64*68];
  __shared__ float sA[64*68];
  const int tid = threadIdx.x;
  const float4* xTr4 = (const float4*)xTr;
  const float4* A4   = (const float4*)Aeff;

  #pragma unroll
  for (int i=0;i<4;i++) {
    int f = tid + i*256;
    int row = f >> 4, kq = f & 15;
    float4 v = xTr4[(m0+row)*16 + kq];
    float vv[4] = {v.x,v.y,v.z,v.w};
    float4 w = A4[(g0+row)*16 + kq];
    float wv[4] = {w.x,w.y,w.z,w.w};
    #pragma unroll
    for (int q=0;q<4;q++) {
      sX[(kq*4+q)*68 + row] = vv[q];
      sA[(kq*4+q)*68 + row] = wv[q];
    }
  }
  __syncthreads();

  const int tm = tid & 15, tn = tid >> 4;
  float acc[4][4] = {};
  #pragma unroll 8
  for (int k=0;k<64;k++) {
    float4 a  = *(const float4*)&sX[k*68 + tm*4];
    float4 bb = *(const float4*)&sA[k*68 + tn*4];
    float av[4]={a.x,a.y,a.z,a.w}, bv[4]={bb.x,bb.y,bb.z,bb.w};
    #pragma unroll
    for (int i=0;i<4;i++)
      #pragma unroll
      for (int j=0;j<4;j++)
        acc[i][j] = fmaf(av[i], bv[j], acc[i][j]);
  }

  float cv[4];
  #pragma unroll
  for (int j=0;j<4;j++) cv[j] = constv[g0 + tn*4 + j];
  #pragma unroll
  for (int i=0;i<4;i++) {
    int mrow = m0 + tm*4 + i;
    #pragma unroll
    for (int j=0;j<4;j++)
      xp[mrow*384 + g0 + tn*4 + j] = acc[i][j] + cv[j];
  }
}

// ---------------------------------------------------------------------------
// K5: biGRU recurrence via MFMA. 8 blocks = (bgroup 0..3, dir); 256 threads
// (4 waves). Each block: 16 batches of one direction. Per step:
//   H[16x64] (bf16, LDS, double-buffered, hidden-major) --tr_b16--> A-frags,
//   12x mfma_f32_16x16x32_bf16 (3 gate tiles x K=64 x Whi/Wlo split),
//   gates fp32 in D-register layout (row=batch=(l>>4)*4+r, col=16w+(l&15)).
// Whh kept as bf16 hi+lo split B-fragments in VGPRs (exact to ~1e-6 rel);
// only h quantization (bf16 RNE, ~4e-3) enters the recurrence.
// ---------------------------------------------------------------------------
__global__ __launch_bounds__(256, 1) void k5_gru(
    const float* __restrict__ xp,
    const float* __restrict__ Whh_f, const float* __restrict__ bhh_f,
    const float* __restrict__ Whh_b, const float* __restrict__ bhh_b,
    float* __restrict__ gru_out)
{
  const int bid = blockIdx.x;           // 0..7
  const int dir = bid & 1;
  const int b0  = (bid >> 1) * 16;
  const int tid = threadIdx.x;
  const int w   = tid >> 6;             // wave 0..3 -> cols 16w..16w+15
  const int l   = tid & 63;
  const int lg  = l >> 4;               // 0..3
  const int li  = l & 15;
  const int col = w*16 + li;            // hidden unit 0..63

  const float* Whh = dir ? Whh_b : Whh_f;
  const float* bhh = dir ? bhh_b : bhh_f;

  // ---- preload B fragments: B[k][col] = Whh[G*64+col][k], bf16 hi+lo ----
  bf16x8 W1[3][2], W2[3][2];
  float bias[3];
  #pragma unroll
  for (int G=0; G<3; ++G) {
    const int grow = G*64 + col;
    bias[G] = bhh[grow];
    #pragma unroll
    for (int m=0; m<2; ++m) {
      const float* p0 = &Whh[grow*64 + lg*4 + 32*m];
      float a[8];
      a[0]=p0[0];  a[1]=p0[1];  a[2]=p0[2];  a[3]=p0[3];
      a[4]=p0[16]; a[5]=p0[17]; a[6]=p0[18]; a[7]=p0[19];
      bf16x8 hi, lo;
      #pragma unroll
      for (int q=0;q<8;q++){
        ushort h1 = f2bf(a[q]);
        ushort h2 = f2bf(a[q] - bf2f(h1));
        hi[q] = (short)h1; lo[q] = (short)h2;
      }
      W1[G][m]=hi; W2[G][m]=lo;
    }
  }

  __shared__ ushort Ht[2][1024];        // [buf][h*16 + batch], bf16

  float hprev[4] = {0.f,0.f,0.f,0.f};
  const int goff = dir*192;

  float xq[3][4];
  const int t0 = dir ? (Tt-1) : 0;
  #pragma unroll
  for (int G=0;G<3;G++)
    #pragma unroll
    for (int r=0;r<4;r++) {
      int gb = b0 + lg*4 + r;
      xq[G][r] = xp[((size_t)gb*Tt + t0)*384 + goff + G*64 + col];
    }

  const unsigned ldsbase = (unsigned)(uintptr_t)(&Ht[0][0]);
  const unsigned myrd = ldsbase + li*2 + lg*128;   // per-lane tr-read base
  const unsigned mywr = col*16 + lg*4;             // ushort index for write

  for (int s=0; s<Tt; ++s) {
    const int t = dir ? (Tt-1-s) : s;
    const int buf = s & 1;

    ushort4 hb;
    hb.x = f2bf(hprev[0]); hb.y = f2bf(hprev[1]);
    hb.z = f2bf(hprev[2]); hb.w = f2bf(hprev[3]);
    *(ushort4*)&Ht[buf][mywr] = hb;
    __syncthreads();

    uint2 a0,a1,a2,a3;
    unsigned ra = myrd + buf*2048;
    asm volatile("ds_read_b64_tr_b16 %0, %4 offset:0\n\t"
                 "ds_read_b64_tr_b16 %1, %4 offset:512\n\t"
                 "ds_read_b64_tr_b16 %2, %4 offset:1024\n\t"
                 "ds_read_b64_tr_b16 %3, %4 offset:1536"
                 : "=&v"(a0), "=&v"(a1), "=&v"(a2), "=&v"(a3)
                 : "v"(ra) : "memory");

    // prefetch next-step xp while tr-reads are in flight
    float xqn[3][4];
    if (s < Tt-1) {
      int tn2 = dir ? (Tt-2-s) : (s+1);
      #pragma unroll
      for (int G=0;G<3;G++)
        #pragma unroll
        for (int r=0;r<4;r++) {
          int gb = b0 + lg*4 + r;
          xqn[G][r] = xp[((size_t)gb*Tt + tn2)*384 + goff + G*64 + col];
        }
    }

    asm volatile("s_waitcnt lgkmcnt(0)" ::: "memory");
    __builtin_amdgcn_sched_barrier(0);

    union { uint2 u[2]; bf16x8 v; } A0u, A1u;
    A0u.u[0]=a0; A0u.u[1]=a1;           // k 0..31
    A1u.u[0]=a2; A1u.u[1]=a3;           // k 32..63

    f32x4 acc[3];
    #pragma unroll
    for (int G=0;G<3;G++){
      f32x4 z4 = {0.f,0.f,0.f,0.f};
      z4 = __builtin_amdgcn_mfma_f32_16x16x32_bf16(A0u.v, W1[G][0], z4, 0,0,0);
      z4 = __builtin_amdgcn_mfma_f32_16x16x32_bf16(A1u.v, W1[G][1], z4, 0,0,0);
      z4 = __builtin_amdgcn_mfma_f32_16x16x32_bf16(A0u.v, W2[G][0], z4, 0,0,0);
      z4 = __builtin_amdgcn_mfma_f32_16x16x32_bf16(A1u.v, W2[G][1], z4, 0,0,0);
      acc[G] = z4;
    }

    #pragma unroll
    for (int r=0;r<4;r++){
      float hr_ = acc[0][r] + bias[0];
      float hz_ = acc[1][r] + bias[1];
      float hn_ = acc[2][r] + bias[2];
      float rr  = sigm(xq[0][r] + hr_);
      float zz  = sigm(xq[1][r] + hz_);
      float nn2 = tanh_fast(xq[2][r] + rr*hn_);
      float hnew = (1.f-zz)*nn2 + zz*hprev[r];
      hprev[r] = hnew;
      int gb = b0 + lg*4 + r;
      gru_out[((size_t)gb*Tt + t)*128 + dir*64 + col] = hnew;
    }

    if (s < Tt-1) {
      #pragma unroll
      for (int G=0;G<3;G++)
        #pragma unroll
        for (int r=0;r<4;r++) xq[G][r]=xqn[G][r];
    }
  }
}

// ---------------------------------------------------------------------------
// K6: attention pooling + classifier. One block per batch item.
// ---------------------------------------------------------------------------
__global__ __launch_bounds__(256) void k6_attn(
    const float* __restrict__ gru_out,
    const float* __restrict__ attn_W, const float* __restrict__ attn_b,
    const float* __restrict__ clf_W,  const float* __restrict__ clf_b,
    float* __restrict__ out)
{
  const int b = blockIdx.x, tid = threadIdx.x;
  __shared__ float s_s[Tt];
  __shared__ float red[256];
  __shared__ float aW[128], cW[128];
  if (tid < 128) { aW[tid]=attn_W[tid]; cW[tid]=clf_W[tid]; }
  __syncthreads();

  if (tid < Tt) {
    const float* row = gru_out + (b*Tt + tid)*128;
    float acc = 0.f;
    for (int j=0;j<128;j++) acc = fmaf(row[j], aW[j], acc);
    s_s[tid] = tanhf(acc + attn_b[0]);
  }
  __syncthreads();

  red[tid] = (tid < Tt) ? s_s[tid] : -1e30f;
  __syncthreads();
  for (int s2=128;s2;s2>>=1){ if(tid<s2) red[tid]=fmaxf(red[tid],red[tid+s2]); __syncthreads(); }
  float mx = red[0];
  __syncthreads();

  float e = 0.f;
  if (tid < Tt) { e = expf(s_s[tid]-mx); s_s[tid] = e; }
  red[tid] = e;
  __syncthreads();
  for (int s2=128;s2;s2>>=1){ if(tid<s2) red[tid]+=red[tid+s2]; __syncthreads(); }
  float total = red[0];
  __syncthreads();

  float p = 0.f;
  if (tid < 128) {
    float c = 0.f;
    for (int t=0;t<Tt;t++) c = fmaf(s_s[t], gru_out[(b*Tt+t)*128 + tid], c);
    p = (c/total)*cW[tid];
  }
  red[tid] = p;
  __syncthreads();
  for (int s2=128;s2;s2>>=1){ if(tid<s2) red[tid]+=red[tid+s2]; __syncthreads(); }
  if (tid==0) out[b] = sigm(red[0] + clf_b[0]);
}

// ---------------------------------------------------------------------------
extern "C" void kernel_launch(void* const* d_in, const int* in_sizes, int n_in,
                              void* d_out, int out_size, void* d_ws, size_t ws_size,
                              hipStream_t stream)
{
  const float* x      = (const float*)d_in[0];
  const int*   sp_ei  = (const int*)  d_in[1];
  const float* sp_ew  = (const float*)d_in[2];
  const int*   fn_ei  = (const int*)  d_in[3];
  const float* fn_ew  = (const float*)d_in[4];
  const float* Wcheb  = (const float*)d_in[5];
  const float* bcheb  = (const float*)d_in[6];
  const float* Wgcn   = (const float*)d_in[7];
  const float* bgcn   = (const float*)d_in[8];
  const float* Wih_f  = (const float*)d_in[9];
  const float* Whh_f  = (const float*)d_in[10];
  const float* bih_f  = (const float*)d_in[11];
  const float* bhh_f  = (const float*)d_in[12];
  const float* Wih_b  = (const float*)d_in[13];
  const float* Whh_b  = (const float*)d_in[14];
  const float* bih_b  = (const float*)d_in[15];
  const float* bhh_b  = (const float*)d_in[16];
  const float* attn_W = (const float*)d_in[17];
  const float* attn_b = (const float*)d_in[18];
  const float* clf_W  = (const float*)d_in[19];
  const float* clf_b  = (const float*)d_in[20];
  float* out = (float*)d_out;

  float* ws     = (float*)d_ws;
  float* Lg     = ws;                    // 4096
  float* L2g    = Lg   + 4096;           // 4096
  float* Gm     = L2g  + 4096;           // 4096
  float* Aeff   = Gm   + 4096;           // 384*64 = 24576
  float* constv = Aeff + 24576;          // 384 (+pad to 512)
  float* xTr    = constv + 512;          // 12800*64 = 819200
  float* xp     = xTr  + 819200;         // 12800*384 = 4915200
  float* gro    = xp   + 4915200;        // 12800*128 = 1638400

  hipLaunchKernelGGL(k1_graphs,    dim3(1),      dim3(256), 0, stream,
                     sp_ei, sp_ew, fn_ei, fn_ew, Lg, L2g, Gm);
  hipLaunchKernelGGL(k3_transpose, dim3(64),     dim3(256), 0, stream, x, xTr);
  hipLaunchKernelGGL(k2_aeff,      dim3(384),    dim3(64),  0, stream,
                     Wih_f, bih_f, Wih_b, bih_b, Wcheb, bcheb, Wgcn, bgcn,
                     Lg, L2g, Gm, Aeff, constv);
  hipLaunchKernelGGL(k4_gemm,      dim3(200, 6), dim3(256), 0, stream,
                     xTr, Aeff, constv, xp);
  hipLaunchKernelGGL(k5_gru,       dim3(8),      dim3(256), 0, stream,
                     xp, Whh_f, bhh_f, Whh_b, bhh_b, gro);
  hipLaunchKernelGGL(k6_attn,      dim3(64),     dim3(256), 0, stream,
                     gro, attn_W, attn_b, clf_W, clf_b, out);
}

// Round 4
// 164.032 us; speedup vs baseline: 1.5322x; 1.5322x over previous
//
#include <hip/hip_runtime.h>
#include <math.h>

#define Nn 64
#define Tt 200
#define Bb 64

__device__ __forceinline__ float sigm(float x){ return 1.0f/(1.0f+__expf(-x)); }
__device__ __forceinline__ float tanh_fast(float x){
  x = fminf(fmaxf(x, -15.f), 15.f);
  float e = __expf(-2.f*x);
  return (1.f - e)/(1.f + e);
}

typedef __attribute__((ext_vector_type(4))) float f4;

// ---------------------------------------------------------------------------
// K1: build graph operators. L = -S_cheb, L2 = 2*S@S - I, G = S_gcn (+diag).
// Single block, 256 threads. Edge scatter via LDS atomics; S padded to
// stride 68 so the S@S phase uses conflict-free f4 row reads.
// ---------------------------------------------------------------------------
__global__ __launch_bounds__(256) void k1_graphs(
    const int* __restrict__ sp_ei, const float* __restrict__ sp_ew,
    const int* __restrict__ fn_ei, const float* __restrict__ fn_ew,
    float* __restrict__ Lg, float* __restrict__ L2g, float* __restrict__ Gm)
{
  __shared__ float deg[Nn];
  __shared__ float dinv[Nn];
  __shared__ float S[64*68];            // padded stride 68
  const int tid = threadIdx.x;

  // ---- ChebConv operator (512 edges) ----
  if (tid < Nn) deg[tid] = 0.f;
  for (int i=tid;i<64*68;i+=256) S[i]=0.f;
  __syncthreads();
  for (int e=tid;e<512;e+=256) atomicAdd(&deg[sp_ei[e]], sp_ew[e]);   // deg over row
  __syncthreads();
  if (tid < Nn) dinv[tid] = (deg[tid] > 0.f) ? rsqrtf(deg[tid]) : 0.f;
  __syncthreads();
  for (int e=tid;e<512;e+=256) {
    int r = sp_ei[e], c = sp_ei[512+e];
    atomicAdd(&S[c*68 + r], dinv[r]*sp_ew[e]*dinv[c]);
  }
  __syncthreads();
  for (int i=tid;i<4096;i+=256) Lg[i] = -S[(i>>6)*68 + (i&63)];   // Ltil = -S
  // L2 = 2*S@S - I : thread -> row n = tid>>2, 16 cols at mb=(tid&3)*16
  {
    const int n = tid>>2, mb = (tid&3)*16;
    float a[16];
    #pragma unroll
    for (int q=0;q<16;q++) a[q]=0.f;
    for (int j=0;j<64;j++){
      float snj = S[n*68+j];
      const float4* rj = (const float4*)&S[j*68+mb];
      #pragma unroll
      for (int q=0;q<4;q++){
        float4 v = rj[q];
        a[q*4+0]=fmaf(snj,v.x,a[q*4+0]);
        a[q*4+1]=fmaf(snj,v.y,a[q*4+1]);
        a[q*4+2]=fmaf(snj,v.z,a[q*4+2]);
        a[q*4+3]=fmaf(snj,v.w,a[q*4+3]);
      }
    }
    #pragma unroll
    for (int q=0;q<16;q++){
      int m = mb+q;
      L2g[n*64+m] = 2.f*a[q] - (n==m ? 1.f : 0.f);
    }
  }
  __syncthreads();   // all reads of S done before reuse

  // ---- GCNConv operator (1024 edges) ----
  if (tid < Nn) deg[tid] = 0.f;
  for (int i=tid;i<64*68;i+=256) S[i]=0.f;
  __syncthreads();
  for (int e=tid;e<1024;e+=256) atomicAdd(&deg[fn_ei[1024+e]], fn_ew[e]);  // deg over col
  __syncthreads();
  if (tid < Nn) dinv[tid] = rsqrtf(deg[tid] + 1.f);
  __syncthreads();
  for (int e=tid;e<1024;e+=256) {
    int r = fn_ei[e], c = fn_ei[1024+e];
    atomicAdd(&S[c*68 + r], dinv[r]*fn_ew[e]*dinv[c]);
  }
  __syncthreads();
  if (tid < Nn) S[tid*68 + tid] += dinv[tid]*dinv[tid];     // + diag(1/deg)
  __syncthreads();
  for (int i=tid;i<4096;i+=256) Gm[i] = S[(i>>6)*68 + (i&63)];
}

// ---------------------------------------------------------------------------
// K2: fold Wih (+Wcheb/Wgcn/graph ops) into Aeff[384][64] and constv[384].
// ---------------------------------------------------------------------------
__global__ __launch_bounds__(64) void k2_aeff(
    const float* __restrict__ Wih_f, const float* __restrict__ bih_f,
    const float* __restrict__ Wih_b, const float* __restrict__ bih_b,
    const float* __restrict__ Wcheb, const float* __restrict__ bcheb,
    const float* __restrict__ Wgcn,  const float* __restrict__ bgcn,
    const float* __restrict__ Lg, const float* __restrict__ L2g,
    const float* __restrict__ Gm,
    float* __restrict__ Aeff, float* __restrict__ constv)
{
  const int g = blockIdx.x;                 // 0..383
  const int dir = (g >= 192) ? 1 : 0;
  const int grow = dir ? g - 192 : g;
  const float* Wih = dir ? Wih_b : Wih_f;
  const float* bih = dir ? bih_b : bih_f;

  __shared__ float wrow[64*129];
  __shared__ float arow[256];
  const int tid = threadIdx.x;              // 64 threads = 1 wave

  for (int i = tid; i < 8192; i += 64)
    wrow[(i>>7)*129 + (i&127)] = Wih[grow*8192 + i];
  __syncthreads();

  const int n = tid;
  float a0=0.f,a1=0.f,a2=0.f,a3=0.f,cp=0.f;
  for (int c=0;c<64;c++) {
    float w1 = wrow[n*129 + c];
    a0 = fmaf(w1, Wcheb[c],     a0);
    a1 = fmaf(w1, Wcheb[64+c],  a1);
    a2 = fmaf(w1, Wcheb[128+c], a2);
    cp = fmaf(w1, bcheb[c],     cp);
    float w2 = wrow[n*129 + 64 + c];
    a3 = fmaf(w2, Wgcn[c], a3);
    cp = fmaf(w2, bgcn[c], cp);
  }
  arow[n*4+0]=a0; arow[n*4+1]=a1; arow[n*4+2]=a2; arow[n*4+3]=a3;
  for (int off=32; off; off>>=1) cp += __shfl_down(cp, off, 64);
  if (tid==0) constv[g] = cp + bih[grow];
  __syncthreads();

  const int m = tid;
  float ae = arow[m*4+0];
  for (int nn2=0; nn2<64; nn2++) {
    ae = fmaf(arow[nn2*4+1], Lg [nn2*64+m], ae);
    ae = fmaf(arow[nn2*4+2], L2g[nn2*64+m], ae);
    ae = fmaf(arow[nn2*4+3], Gm [nn2*64+m], ae);
  }
  Aeff[g*64+m] = ae;
}

// ---------------------------------------------------------------------------
// K3: transpose x[B][N][T] -> xTr[B*T][N]
// ---------------------------------------------------------------------------
__global__ __launch_bounds__(256) void k3_transpose(
    const float* __restrict__ x, float* __restrict__ xTr)
{
  const int b = blockIdx.x;
  for (int idx = threadIdx.x; idx < Tt*Nn; idx += 256) {
    int t = idx >> 6, m = idx & 63;
    xTr[(b*Tt + t)*64 + m] = x[(b*64 + m)*Tt + t];
  }
}

// ---------------------------------------------------------------------------
// K4: xp[12800][384] = xTr[12800][64] @ Aeff[384][64]^T + constv
// ---------------------------------------------------------------------------
__global__ __launch_bounds__(256) void k4_gemm(
    const float* __restrict__ xTr, const float* __restrict__ Aeff,
    const float* __restrict__ constv, float* __restrict__ xp)
{
  const int m0 = blockIdx.x*64, g0 = blockIdx.y*64;
  __shared__ float sX[64*68];
  __shared__ float sA[64*68];
  const int tid = threadIdx.x;
  const float4* xTr4 = (const float4*)xTr;
  const float4* A4   = (const float4*)Aeff;

  #pragma unroll
  for (int i=0;i<4;i++) {
    int f = tid + i*256;
    int row = f >> 4, kq = f & 15;
    float4 v = xTr4[(m0+row)*16 + kq];
    float vv[4] = {v.x,v.y,v.z,v.w};
    float4 w = A4[(g0+row)*16 + kq];
    float wv[4] = {w.x,w.y,w.z,w.w};
    #pragma unroll
    for (int q=0;q<4;q++) {
      sX[(kq*4+q)*68 + row] = vv[q];
      sA[(kq*4+q)*68 + row] = wv[q];
    }
  }
  __syncthreads();

  const int tm = tid & 15, tn = tid >> 4;
  float acc[4][4] = {};
  #pragma unroll 8
  for (int k=0;k<64;k++) {
    float4 a  = *(const float4*)&sX[k*68 + tm*4];
    float4 bb = *(const float4*)&sA[k*68 + tn*4];
    float av[4]={a.x,a.y,a.z,a.w}, bv[4]={bb.x,bb.y,bb.z,bb.w};
    #pragma unroll
    for (int i=0;i<4;i++)
      #pragma unroll
      for (int j=0;j<4;j++)
        acc[i][j] = fmaf(av[i], bv[j], acc[i][j]);
  }

  float cv[4];
  #pragma unroll
  for (int j=0;j<4;j++) cv[j] = constv[g0 + tn*4 + j];
  #pragma unroll
  for (int i=0;i<4;i++) {
    int mrow = m0 + tm*4 + i;
    #pragma unroll
    for (int j=0;j<4;j++)
      xp[mrow*384 + g0 + tn*4 + j] = acc[i][j] + cv[j];
  }
}

// ---------------------------------------------------------------------------
// K5: biGRU recurrence. 128 blocks = (b, dir); 192 threads (3 waves).
// Thread g owns ONE gate row: 64 fp32 weights = 64 VGPRs (resident; R1's
// 192/lane spilled at the 120-reg allocation). h broadcast via LDS b128
// reads; gates on wave 0. xp prefetch depth-2 via x2-unrolled loop with two
// named registers reloaded AFTER use (no rotation -> no per-step vmcnt(0)).
// ---------------------------------------------------------------------------
__global__ __launch_bounds__(192, 1) void k5_gru(
    const float* __restrict__ xp,
    const float* __restrict__ Whh_f, const float* __restrict__ bhh_f,
    const float* __restrict__ Whh_b, const float* __restrict__ bhh_b,
    float* __restrict__ gru_out)
{
  const int bd = blockIdx.x;
  const int b = bd >> 1, dir = bd & 1;
  const int g = threadIdx.x;                // 0..191
  const float* Whh = dir ? Whh_b : Whh_f;
  const float* bhh = dir ? bhh_b : bhh_f;

  f4 w[16];
  #pragma unroll
  for (int j=0;j<16;j++) w[j] = ((const f4*)(Whh + g*64))[j];
  const float bh = bhh[g];

  __shared__ __align__(16) float h_s[64];
  __shared__ float hg_s[192];
  __shared__ float xn_s[64];
  const f4* h4 = (const f4*)h_s;

  float hprev = 0.f;
  if (g < 64) h_s[g] = 0.f;

  const int t0 = dir ? (Tt-1) : 0;
  const int tstep = dir ? -1 : 1;
  const float* xbase = xp + ((size_t)b*Tt)*384 + dir*192 + g;
  float* gout = gru_out + ((size_t)b*Tt)*128 + dir*64 + g;

  float xqA = xbase[(size_t)t0*384];
  float xqB = xbase[(size_t)(t0+tstep)*384];
  __syncthreads();

  int t = t0;
  auto STEP = [&](float& xq) {
    // ---- matvec: hg[g] = w . h  (4 independent FMA chains) ----
    float a0=0.f,a1=0.f,a2=0.f,a3=0.f;
    #pragma unroll
    for (int j=0;j<4;j++){
      f4 w0=w[4*j], w1=w[4*j+1], w2=w[4*j+2], w3=w[4*j+3];
      f4 h0=h4[4*j], h1=h4[4*j+1], h2=h4[4*j+2], h3=h4[4*j+3];
      a0=fmaf(w0.x,h0.x,a0); a0=fmaf(w0.y,h0.y,a0); a0=fmaf(w0.z,h0.z,a0); a0=fmaf(w0.w,h0.w,a0);
      a1=fmaf(w1.x,h1.x,a1); a1=fmaf(w1.y,h1.y,a1); a1=fmaf(w1.z,h1.z,a1); a1=fmaf(w1.w,h1.w,a1);
      a2=fmaf(w2.x,h2.x,a2); a2=fmaf(w2.y,h2.y,a2); a2=fmaf(w2.z,h2.z,a2); a2=fmaf(w2.w,h2.w,a2);
      a3=fmaf(w3.x,h3.x,a3); a3=fmaf(w3.y,h3.y,a3); a3=fmaf(w3.z,h3.z,a3); a3=fmaf(w3.w,h3.w,a3);
    }
    float pre = ((a0+a1)+(a2+a3)) + bh;
    if (g < 128) pre += xq;           // r,z gates: x-part folded in
    else xn_s[g-128] = xq;            // n gate: x-part kept separate
    hg_s[g] = pre;

    // reload this register for step s+2 (used two steps from now)
    int tpre = t + 2*tstep;
    if ((unsigned)tpre < (unsigned)Tt) xq = xbase[(size_t)tpre*384];

    __syncthreads();
    if (g < 64) {
      float r   = sigm(hg_s[g]);
      float z   = sigm(hg_s[64+g]);
      float nng = tanh_fast(xn_s[g] + r*hg_s[128+g]);
      float hnew = (1.f-z)*nng + z*hprev;
      hprev = hnew;
      h_s[g] = hnew;
      gout[(size_t)t*128] = hnew;
    }
    __syncthreads();
    t += tstep;
  };

  for (int sp=0; sp<Tt; sp+=2) {
    STEP(xqA);
    STEP(xqB);
  }
}

// ---------------------------------------------------------------------------
// K6: attention pooling + classifier. One block per batch item.
// ---------------------------------------------------------------------------
__global__ __launch_bounds__(256) void k6_attn(
    const float* __restrict__ gru_out,
    const float* __restrict__ attn_W, const float* __restrict__ attn_b,
    const float* __restrict__ clf_W,  const float* __restrict__ clf_b,
    float* __restrict__ out)
{
  const int b = blockIdx.x, tid = threadIdx.x;
  __shared__ float s_s[Tt];
  __shared__ float red[256];
  __shared__ float aW[128], cW[128];
  if (tid < 128) { aW[tid]=attn_W[tid]; cW[tid]=clf_W[tid]; }
  __syncthreads();

  if (tid < Tt) {
    const float* row = gru_out + (b*Tt + tid)*128;
    float acc = 0.f;
    for (int j=0;j<128;j++) acc = fmaf(row[j], aW[j], acc);
    s_s[tid] = tanhf(acc + attn_b[0]);
  }
  __syncthreads();

  red[tid] = (tid < Tt) ? s_s[tid] : -1e30f;
  __syncthreads();
  for (int s2=128;s2;s2>>=1){ if(tid<s2) red[tid]=fmaxf(red[tid],red[tid+s2]); __syncthreads(); }
  float mx = red[0];
  __syncthreads();

  float e = 0.f;
  if (tid < Tt) { e = expf(s_s[tid]-mx); s_s[tid] = e; }
  red[tid] = e;
  __syncthreads();
  for (int s2=128;s2;s2>>=1){ if(tid<s2) red[tid]+=red[tid+s2]; __syncthreads(); }
  float total = red[0];
  __syncthreads();

  float p = 0.f;
  if (tid < 128) {
    float c = 0.f;
    for (int t=0;t<Tt;t++) c = fmaf(s_s[t], gru_out[(b*Tt+t)*128 + tid], c);
    p = (c/total)*cW[tid];
  }
  red[tid] = p;
  __syncthreads();
  for (int s2=128;s2;s2>>=1){ if(tid<s2) red[tid]+=red[tid+s2]; __syncthreads(); }
  if (tid==0) out[b] = sigm(red[0] + clf_b[0]);
}

// ---------------------------------------------------------------------------
extern "C" void kernel_launch(void* const* d_in, const int* in_sizes, int n_in,
                              void* d_out, int out_size, void* d_ws, size_t ws_size,
                              hipStream_t stream)
{
  const float* x      = (const float*)d_in[0];
  const int*   sp_ei  = (const int*)  d_in[1];
  const float* sp_ew  = (const float*)d_in[2];
  const int*   fn_ei  = (const int*)  d_in[3];
  const float* fn_ew  = (const float*)d_in[4];
  const float* Wcheb  = (const float*)d_in[5];
  const float* bcheb  = (const float*)d_in[6];
  const float* Wgcn   = (const float*)d_in[7];
  const float* bgcn   = (const float*)d_in[8];
  const float* Wih_f  = (const float*)d_in[9];
  const float* Whh_f  = (const float*)d_in[10];
  const float* bih_f  = (const float*)d_in[11];
  const float* bhh_f  = (const float*)d_in[12];
  const float* Wih_b  = (const float*)d_in[13];
  const float* Whh_b  = (const float*)d_in[14];
  const float* bih_b  = (const float*)d_in[15];
  const float* bhh_b  = (const float*)d_in[16];
  const float* attn_W = (const float*)d_in[17];
  const float* attn_b = (const float*)d_in[18];
  const float* clf_W  = (const float*)d_in[19];
  const float* clf_b  = (const float*)d_in[20];
  float* out = (float*)d_out;

  float* ws     = (float*)d_ws;
  float* Lg     = ws;                    // 4096
  float* L2g    = Lg   + 4096;           // 4096
  float* Gm     = L2g  + 4096;           // 4096
  float* Aeff   = Gm   + 4096;           // 384*64 = 24576
  float* constv = Aeff + 24576;          // 384 (+pad to 512)
  float* xTr    = constv + 512;          // 12800*64 = 819200
  float* xp     = xTr  + 819200;         // 12800*384 = 4915200
  float* gro    = xp   + 4915200;        // 12800*128 = 1638400

  hipLaunchKernelGGL(k1_graphs,    dim3(1),      dim3(256), 0, stream,
                     sp_ei, sp_ew, fn_ei, fn_ew, Lg, L2g, Gm);
  hipLaunchKernelGGL(k3_transpose, dim3(64),     dim3(256), 0, stream, x, xTr);
  hipLaunchKernelGGL(k2_aeff,      dim3(384),    dim3(64),  0, stream,
                     Wih_f, bih_f, Wih_b, bih_b, Wcheb, bcheb, Wgcn, bgcn,
                     Lg, L2g, Gm, Aeff, constv);
  hipLaunchKernelGGL(k4_gemm,      dim3(200, 6), dim3(256), 0, stream,
                     xTr, Aeff, constv, xp);
  hipLaunchKernelGGL(k5_gru,       dim3(128),    dim3(192), 0, stream,
                     xp, Whh_f, bhh_f, Whh_b, bhh_b, gro);
  hipLaunchKernelGGL(k6_attn,      dim3(64),     dim3(256), 0, stream,
                     gro, attn_W, attn_b, clf_W, clf_b, out);
}